// Round 9
// baseline (1090.024 us; speedup 1.0000x reference)
//
#include <hip/hip_runtime.h>
#include <hip/hip_cooperative_groups.h>

namespace cg = cooperative_groups;

// Problem constants
#define NV 65536     // flattened vectors (64*32*32)
#define KN 1024      // codebook size
#define DD 256       // embedding dim
#define DECAY_F 0.99f
#define OMD_F (1.0f - 0.99f)
#define EPS_F 1e-5f

typedef __attribute__((ext_vector_type(8))) short short8;
typedef __attribute__((ext_vector_type(16))) float f32x16;

// ---------------------------------------------------------------------------
// async global->LDS 16B copy. LDS dest is wave-uniform base; HW writes
// base + lane*16.
// ---------------------------------------------------------------------------
__device__ __forceinline__ void gl_lds16(const void* g, void* l) {
  __builtin_amdgcn_global_load_lds(
      (const __attribute__((address_space(1))) unsigned int*)g,
      (__attribute__((address_space(3))) unsigned int*)l, 16, 0, 0);
}

// ---------------------------------------------------------------------------
// bf16 split helpers (RTNE)
// ---------------------------------------------------------------------------
__device__ __forceinline__ void bf16_split(float v, short& hi, short& lo) {
  unsigned u = __float_as_uint(v);
  unsigned hr = (u + 0x7FFFu + ((u >> 16) & 1u)) >> 16;
  float hf = __uint_as_float(hr << 16);
  float rem = v - hf;
  unsigned u2 = __float_as_uint(rem);
  unsigned lr = (u2 + 0x7FFFu + ((u2 >> 16) & 1u)) >> 16;
  hi = (short)hr;
  lo = (short)lr;
}

// ---------------------------------------------------------------------------
// Kernel 0 (FUSED): split_x (blocks 0..8191) + prep_e (8192..8223) +
// esq (8224..8479) + ws-zeroing (8480..8737, replaces hipMemsetAsync).
// ---------------------------------------------------------------------------
__global__ __launch_bounds__(256) void prep_all(
    const float* __restrict__ x, const float* __restrict__ emb,
    short* __restrict__ xhi, short* __restrict__ xlo,
    short* __restrict__ eT, float* __restrict__ eSq,
    float* __restrict__ zeroBase) {
  const int b = blockIdx.x;
  if (b < 8192) {
    // ---- split_x: x -> xhi/xlo bf16 arrays (same [N][D] layout) ----
    const int i = (b * 256 + threadIdx.x) * 8;
    float v[8];
    *(float4*)(v + 0) = *(const float4*)(x + i);
    *(float4*)(v + 4) = *(const float4*)(x + i + 4);
    short8 h, l;
    #pragma unroll
    for (int j = 0; j < 8; j++) {
      short hh, ll;
      bf16_split(v[j], hh, ll);
      h[j] = hh; l[j] = ll;
    }
    *(short8*)(xhi + i) = h;
    *(short8*)(xlo + i) = l;
  } else if (b < 8224) {
    // ---- prep_e: e -> MFMA tiled layout.
    // 32 tiles (cc 0..3, dc 0..7), each 16384 shorts:
    //   [h(2)][db(4)][code(256)][8]  global code = cc*256+code, d=dc*32+db*8+j
    const int bb = b - 8192;  // 0..31 = cc*8 + dc
    const int cc = bb >> 3, dc = bb & 7;
    const int c = threadIdx.x;  // code within chunk, 0..255
    const float* src = emb + (cc * 256 + c) * 256 + dc * 32;
    short* tile = eT + bb * 16384;
    #pragma unroll
    for (int db = 0; db < 4; db++) {
      float v[8];
      *(float4*)(v + 0) = *(const float4*)(src + db * 8);
      *(float4*)(v + 4) = *(const float4*)(src + db * 8 + 4);
      short8 h, l;
      #pragma unroll
      for (int j = 0; j < 8; j++) {
        short hh, ll;
        bf16_split(v[j], hh, ll);
        h[j] = hh; l[j] = ll;
      }
      *(short8*)(tile + ((0 * 4 + db) * 256 + c) * 8) = h;
      *(short8*)(tile + ((1 * 4 + db) * 256 + c) * 8) = l;
    }
  } else if (b < 8480) {
    // ---- esq: eSq[k] = ||embedding[k]||^2 (fp32). One wave per row. ----
    const int lane = threadIdx.x & 63;
    const int row = (b - 8224) * 4 + (threadIdx.x >> 6);
    const float4 v = *(const float4*)(emb + row * DD + lane * 4);
    float s = v.x * v.x + v.y * v.y + v.z * v.z + v.w * v.w;
    #pragma unroll
    for (int off = 32; off > 0; off >>= 1) s += __shfl_down(s, off, 64);
    if (lane == 0) eSq[row] = s;
  } else {
    // ---- zero sseSlots(256) + cntI(1024) + dw(262144) = 263424 floats ----
    const int i = ((b - 8480) * 256 + threadIdx.x) * 4;
    if (i < 263424)
      *(float4*)(zeroBase + i) = make_float4(0.0f, 0.0f, 0.0f, 0.0f);
  }
}

// ---------------------------------------------------------------------------
// Kernel 2: MFMA distance + exact best-2 candidates.  (R8 verbatim: counted
// vmcnt double-buffer, best measured 126.5 us, no spill.)
// ---------------------------------------------------------------------------
__global__ __launch_bounds__(256, 2) void argmin_mfma(
    const short* __restrict__ xhi, const short* __restrict__ xlo,
    const short* __restrict__ eT, const float* __restrict__ eSq,
    int2* __restrict__ cand) {
  __shared__ __align__(16) char uS[67584];  // union: 2x32K stage / 66K fold
  __shared__ float eSqS[1024];

  float2* dbAll = (float2*)uS;

  const int tid = threadIdx.x;
  const int lane = tid & 63;
  const int wid = tid >> 6;
  const int l31 = lane & 31;
  const int lh = lane >> 5;
  const int qBase = blockIdx.x * 128 + wid * 32;

  // stage eSq once (1024 floats)
  *(float4*)(eSqS + tid * 4) = *(const float4*)(eSq + tid * 4);
  __syncthreads();  // eSqS visible to all waves BEFORE first es2 read

  float2* dbW = dbAll + wid * (64 * 33);

  float b1d = 3.4e38f, b2d = 3.4e38f;
  int b1k = 0, b2k = 1;

  const int qRow = (qBase + l31) * DD;   // fits 32-bit (16.7M max)

  const int wbase = wid * 1024;   // wave-uniform LDS sub-base (stage split)
  const int lane16 = lane * 16;   // per-lane global offset

  for (int cc = 0; cc < 4; cc++) {
    __syncthreads();  // prev-cc fold reads done / eSqS visible (cc=0)

    // prologue: stage tile (cc,0) into buf0 (8 VMEM ops outstanding)
    {
      const char* src = (const char*)(eT + (cc * 8 + 0) * 16384);
      #pragma unroll
      for (int i = 0; i < 8; i++)
        gl_lds16(src + i * 4096 + wbase + lane16, uS + i * 4096 + wbase);
    }

    f32x16 acc[8];
    #pragma unroll
    for (int ct = 0; ct < 8; ct++)
      #pragma unroll
      for (int i = 0; i < 16; i++) acc[ct][i] = 0.0f;

    float es2[8];
    #pragma unroll
    for (int ct = 0; ct < 8; ct++) es2[ct] = eSqS[cc * 256 + ct * 32 + l31];

    for (int dc = 0; dc < 8; dc++) {
      const int cur = dc & 1;
      const short* eS = (const short*)(uS + cur * 32768);

      // A-fragments (4 VMEM loads), pinned BEFORE the stage-next block.
      short8 ahi0, alo0, ahi1, alo1;
      {
        const int d0 = dc * 32 + lh * 8;
        const int d1 = d0 + 16;
        ahi0 = *(const short8*)(xhi + qRow + d0);
        alo0 = *(const short8*)(xlo + qRow + d0);
        ahi1 = *(const short8*)(xhi + qRow + d1);
        alo1 = *(const short8*)(xlo + qRow + d1);
      }
      __builtin_amdgcn_sched_barrier(0);

      if (dc < 7) {
        const char* src = (const char*)(eT + (cc * 8 + dc + 1) * 16384);
        char* dst = uS + (cur ^ 1) * 32768;
        #pragma unroll
        for (int i = 0; i < 8; i++)
          gl_lds16(src + i * 4096 + wbase + lane16, dst + i * 4096 + wbase);
        // outstanding: tile_dc(8 oldest) + A(4) + stage_next(8) = 20
        asm volatile("s_waitcnt vmcnt(12)" ::: "memory");
      } else {
        // outstanding: tile_7(8) + A(4) = 12
        asm volatile("s_waitcnt vmcnt(4)" ::: "memory");
      }
      __builtin_amdgcn_s_barrier();   // all waves: tile dc fully in LDS
      asm volatile("" ::: "memory");

      // MFMA phase on buf[cur]
      #pragma unroll
      for (int ks = 0; ks < 2; ks++) {
        const short8 ahi = ks ? ahi1 : ahi0;
        const short8 alo = ks ? alo1 : alo0;
        const int db = ks * 2 + lh;
        #pragma unroll
        for (int ct = 0; ct < 8; ct++) {
          const int cL = ct * 32 + l31;
          const short8 bhi = *(const short8*)(eS + ((0 * 4 + db) * 256 + cL) * 8);
          const short8 blo = *(const short8*)(eS + ((1 * 4 + db) * 256 + cL) * 8);
          acc[ct] = __builtin_amdgcn_mfma_f32_32x32x16_bf16(ahi, bhi, acc[ct], 0, 0, 0);
          acc[ct] = __builtin_amdgcn_mfma_f32_32x32x16_bf16(ahi, blo, acc[ct], 0, 0, 0);
          acc[ct] = __builtin_amdgcn_mfma_f32_32x32x16_bf16(alo, bhi, acc[ct], 0, 0, 0);
        }
      }

      asm volatile("" ::: "memory");
      __builtin_amdgcn_s_barrier();   // all waves done reading buf[cur]
      asm volatile("" ::: "memory");
    }

    __syncthreads();  // all waves past MFMA reads; uS becomes fold buffer

    // per-(lane,reg): exact best2 over the 8 ct codes; transpose via LDS.
    #pragma unroll
    for (int r = 0; r < 16; r++) {
      const int row = (r & 3) + 8 * (r >> 2) + 4 * lh;  // query row 0..31
      float cb1 = 3.4e38f, cb2 = 3.4e38f;
      int ck1 = 0, ck2 = 0;
      #pragma unroll
      for (int ct = 0; ct < 8; ct++) {
        const float dd = es2[ct] - 2.0f * acc[ct][r];
        const int k = cc * 256 + ct * 32 + l31;
        if (dd < cb1) { cb2 = cb1; ck2 = ck1; cb1 = dd; ck1 = k; }
        else if (dd < cb2) { cb2 = dd; ck2 = k; }
      }
      dbW[(l31 * 2 + 0) * 33 + row] = make_float2(cb1, __int_as_float(ck1));
      dbW[(l31 * 2 + 1) * 33 + row] = make_float2(cb2, __int_as_float(ck2));
    }
    __syncthreads();  // transpose visible

    #pragma unroll
    for (int i = 0; i < 32; i++) {
      const float2 c = dbW[(lh * 32 + i) * 33 + l31];
      const float dd = c.x;
      const int k = __float_as_int(c.y);
      if (dd < b1d) { b2d = b1d; b2k = b1k; b1d = dd; b1k = k; }
      else if (dd < b2d) { b2d = dd; b2k = k; }
    }
  }

  // merge lane pairs (l, l+32): exact best2 of the union, k-tiebreak
  {
    const float p1d = __shfl_xor(b1d, 32, 64);
    const int p1k = __shfl_xor(b1k, 32, 64);
    const float p2d = __shfl_xor(b2d, 32, 64);
    const int p2k = __shfl_xor(b2k, 32, 64);
    if ((p1d < b1d) || (p1d == b1d && p1k < b1k)) {
      b2d = b1d; b2k = b1k; b1d = p1d; b1k = p1k;
    } else if ((p1d < b2d) || (p1d == b2d && p1k < b2k)) {
      b2d = p1d; b2k = p1k;
    }
    if ((p2d < b1d) || (p2d == b1d && p2k < b1k)) {
      b2d = b1d; b2k = b1k; b1d = p2d; b1k = p2k;
    } else if ((p2d < b2d) || (p2d == b2d && p2k < b2k)) {
      b2d = p2d; b2k = p2k;
    }
  }
  if (lh == 0) cand[qBase + l31] = make_int2(b1k, b2k);
}

// ---------------------------------------------------------------------------
// Kernel 3 (COOPERATIVE TAIL): gather_rescue + scan/finalize1 + scatter +
// dw_sum + finalize2 in ONE dispatch with grid syncs. Replaces 5 dispatches
// (4 launch/drain boundaries eliminated). 1024 blocks x 256 thr,
// __launch_bounds__(256,4) -> <=128 VGPR -> 4 blk/CU co-residency (1024 fit).
// No early returns anywhere: every thread reaches every grid.sync().
// ---------------------------------------------------------------------------
__global__ __launch_bounds__(256, 4) void tail_coop(
    const float* __restrict__ x, const float* __restrict__ emb,
    const int2* __restrict__ cand, const float* __restrict__ ema_cs,
    const float* __restrict__ ema_w, float* __restrict__ outQ,
    float* __restrict__ outCodes, float* __restrict__ outLoss,
    float* __restrict__ outEmb, float* __restrict__ outCS,
    float* __restrict__ outW, int* __restrict__ idxFinal,
    float* __restrict__ sseSlots, int* __restrict__ cntI,
    int* __restrict__ cursor, int* __restrict__ perm,
    float* __restrict__ dw, float* __restrict__ norm) {
  cg::grid_group grid = cg::this_grid();
  const int tid = threadIdx.x;
  const int lane = tid & 63;
  const int w = tid >> 6;

  __shared__ int sInt[256];
  __shared__ float sF[256];
  __shared__ int sp[128];

  // ---- phase 0: gather_rescue (grid-stride; 4096 waves x 16 queries) ----
  {
    const int waveId = blockIdx.x * 4 + w;
    for (int n = waveId; n < NV; n += 4096) {
      const int2 kk = cand[n];
      const float4 xv = *(const float4*)(x + n * DD + lane * 4);
      const float4 e1 = *(const float4*)(emb + kk.x * DD + lane * 4);
      const float4 e2 = *(const float4*)(emb + kk.y * DD + lane * 4);

      float p1 = e1.x * (e1.x - 2.0f * xv.x) + e1.y * (e1.y - 2.0f * xv.y) +
                 e1.z * (e1.z - 2.0f * xv.z) + e1.w * (e1.w - 2.0f * xv.w);
      float p2 = e2.x * (e2.x - 2.0f * xv.x) + e2.y * (e2.y - 2.0f * xv.y) +
                 e2.z * (e2.z - 2.0f * xv.z) + e2.w * (e2.w - 2.0f * xv.w);
      #pragma unroll
      for (int m = 32; m > 0; m >>= 1) {
        p1 += __shfl_xor(p1, m, 64);
        p2 += __shfl_xor(p2, m, 64);
      }
      const bool pick2 = (p2 < p1) || (p2 == p1 && kk.y < kk.x);
      const int ksel = pick2 ? kk.y : kk.x;
      const float4 ev = pick2 ? e2 : e1;

      *(float4*)(outQ + n * DD + lane * 4) = ev;

      const float d0 = ev.x - xv.x, d1 = ev.y - xv.y, d2 = ev.z - xv.z,
                  d3 = ev.w - xv.w;
      float s = d0 * d0 + d1 * d1 + d2 * d2 + d3 * d3;
      #pragma unroll
      for (int m = 32; m > 0; m >>= 1) s += __shfl_down(s, m, 64);
      if (lane == 0) {
        atomicAdd(&sseSlots[n & 255], s);
        atomicAdd(&cntI[ksel], 1);
        idxFinal[n] = ksel;
        outCodes[n] = (float)ksel;
      }
    }
  }
  __threadfence();
  grid.sync();

  // ---- phase 1: scan + finalize1 (block 0 only; 4 codes per thread) ----
  if (blockIdx.x == 0) {
    const int4 c4 = *(const int4*)(cntI + tid * 4);
    const int l0 = c4.x, l01 = c4.x + c4.y, l012 = l01 + c4.z;
    const int ltot = l012 + c4.w;
    sInt[tid] = ltot;
    __syncthreads();
    #pragma unroll
    for (int off = 1; off < 256; off <<= 1) {
      const int add = (tid >= off) ? sInt[tid - off] : 0;
      __syncthreads();
      sInt[tid] += add;
      __syncthreads();
    }
    const int excl = sInt[tid] - ltot;
    cursor[tid * 4 + 0] = excl;
    cursor[tid * 4 + 1] = excl + l0;
    cursor[tid * 4 + 2] = excl + l01;
    cursor[tid * 4 + 3] = excl + l012;

    // finalize1: new_cluster_size, n-sum, norm, losses
    const float4 ecs = *(const float4*)(ema_cs + tid * 4);
    float nc[4];
    nc[0] = DECAY_F * ecs.x + OMD_F * (float)c4.x;
    nc[1] = DECAY_F * ecs.y + OMD_F * (float)c4.y;
    nc[2] = DECAY_F * ecs.z + OMD_F * (float)c4.z;
    nc[3] = DECAY_F * ecs.w + OMD_F * (float)c4.w;
    *(float4*)(outCS + tid * 4) = make_float4(nc[0], nc[1], nc[2], nc[3]);
    sF[tid] = nc[0] + nc[1] + nc[2] + nc[3];
    __syncthreads();
    #pragma unroll
    for (int s = 128; s > 0; s >>= 1) {
      if (tid < s) sF[tid] += sF[tid + s];
      __syncthreads();
    }
    const float nTot = sF[0];
    __syncthreads();
    const float den = nTot + (float)KN * EPS_F;
    float4 nm;
    nm.x = (nc[0] + EPS_F) / den * nTot;
    nm.y = (nc[1] + EPS_F) / den * nTot;
    nm.z = (nc[2] + EPS_F) / den * nTot;
    nm.w = (nc[3] + EPS_F) / den * nTot;
    *(float4*)(norm + tid * 4) = nm;

    sF[tid] = sseSlots[tid];
    __syncthreads();
    #pragma unroll
    for (int s = 128; s > 0; s >>= 1) {
      if (tid < s) sF[tid] += sF[tid + s];
      __syncthreads();
    }
    if (tid == 0) {
      const float mse = sF[0] * (1.0f / 16777216.0f);
      outLoss[0] = 0.25f * mse;  // commitment
      outLoss[1] = mse;          // codebook
    }
  }
  __threadfence();
  grid.sync();

  // ---- phase 2: scatter (counting sort; blocks 0..255 active) ----
  {
    const int n = blockIdx.x * 256 + tid;
    if (n < NV) {
      const int k = idxFinal[n];
      const int pos = atomicAdd(&cursor[k], 1);
      perm[pos] = (k << 16) | n;
    }
  }
  __threadfence();
  grid.sync();

  // ---- phase 3: dw_sum (blocks 0..511; wave owns 32 consecutive rows) ----
  if (blockIdx.x < 512) {
    if (tid < 128) sp[tid] = perm[blockIdx.x * 128 + tid];
    __syncthreads();
    const int* wp = sp + w * 32;

    float4 acc = make_float4(0.0f, 0.0f, 0.0f, 0.0f);
    int kcur = wp[0] >> 16;

    #pragma unroll
    for (int c = 0; c < 4; c++) {
      float4 v[8];
      int kk[8];
      #pragma unroll
      for (int j = 0; j < 8; j++) {
        const int p = wp[c * 8 + j];
        kk[j] = p >> 16;
        v[j] = *(const float4*)(x + (long)(p & 0xFFFF) * DD + lane * 4);
      }
      #pragma unroll
      for (int j = 0; j < 8; j++) {
        if (kk[j] != kcur) {
          float* drow = dw + kcur * DD + lane * 4;
          atomicAdd(drow + 0, acc.x);
          atomicAdd(drow + 1, acc.y);
          atomicAdd(drow + 2, acc.z);
          atomicAdd(drow + 3, acc.w);
          acc = make_float4(0.0f, 0.0f, 0.0f, 0.0f);
          kcur = kk[j];
        }
        acc.x += v[j].x; acc.y += v[j].y;
        acc.z += v[j].z; acc.w += v[j].w;
      }
    }
    {
      float* drow = dw + kcur * DD + lane * 4;
      atomicAdd(drow + 0, acc.x);
      atomicAdd(drow + 1, acc.y);
      atomicAdd(drow + 2, acc.z);
      atomicAdd(drow + 3, acc.w);
    }
  }
  __threadfence();
  grid.sync();

  // ---- phase 4: finalize2 (1024 blocks x 256 elems = 262144) ----
  {
    const int i = blockIdx.x * 256 + tid;
    const float nw = DECAY_F * ema_w[i] + OMD_F * dw[i];
    outW[i] = nw;
    outEmb[i] = nw / norm[i >> 8];
  }
}

// ---------------------------------------------------------------------------
extern "C" void kernel_launch(void* const* d_in, const int* in_sizes, int n_in,
                              void* d_out, int out_size, void* d_ws, size_t ws_size,
                              hipStream_t stream) {
  const float* x = (const float*)d_in[0];        // [65536, 256]
  const float* emb = (const float*)d_in[1];      // [1024, 256]
  const float* ema_cs = (const float*)d_in[2];   // [1024]
  const float* ema_w = (const float*)d_in[3];    // [1024, 256]
  float* out = (float*)d_out;
  float* ws = (float*)d_ws;

  // --- workspace (float offsets) ---
  float* eSq = ws + 0;                   // 1024
  float* sseSlots = ws + 1024;           // 256   (zeroed by prep_all)
  int* cntI = (int*)(ws + 1280);         // 1024 ints (zeroed by prep_all)
  float* dw = ws + 2304;                 // 262144 (zeroed by prep_all)
  float* norm = ws + 264448;             // 1024
  int* cursor = (int*)(ws + 265472);     // 1024 ints
  int* idxFinal = (int*)(ws + 266496);   // 65536 ints
  int* perm = (int*)(ws + 332032);       // 65536 ints (packed (k<<16)|n)

  // --- d_out doubles as phase-1 scratch (stream-ordered lifetimes) ---
  short* xhi = (short*)out;                     // out[0..8388608)
  short* xlo = (short*)(out + 8388608);         // out[8388608..16777216)
  short* eT = (short*)(out + 16777216);         // 524288 shorts
  int2* cand = (int2*)(out + 17039360);         // 65536 int2

  // --- final output layout (return-order flat, fp32) ---
  float* outQ = out;                    // 16777216  quantized_st
  float* outCodes = out + 16777216;     // 65536     codes (as float)
  float* outLoss = out + 16842752;      // 2         commitment, codebook
  float* outEmb = out + 16842754;       // 262144    new_embedding
  float* outCS = out + 17104898;        // 1024      new_cluster_size
  float* outW = out + 17105922;         // 262144    new_ema_w

  prep_all<<<8738, 256, 0, stream>>>(x, emb, xhi, xlo, eT, eSq, ws + 1024);
  argmin_mfma<<<NV / 128, 256, 0, stream>>>(xhi, xlo, eT, eSq, cand);

  void* args[] = {
      (void*)&x, (void*)&emb, (void*)&cand, (void*)&ema_cs, (void*)&ema_w,
      (void*)&outQ, (void*)&outCodes, (void*)&outLoss, (void*)&outEmb,
      (void*)&outCS, (void*)&outW, (void*)&idxFinal, (void*)&sseSlots,
      (void*)&cntI, (void*)&cursor, (void*)&perm, (void*)&dw, (void*)&norm};
  hipLaunchCooperativeKernel((void*)tail_coop, dim3(1024), dim3(256), args, 0,
                             stream);
}

// Round 10
// 401.969 us; speedup vs baseline: 2.7117x; 2.7117x over previous
//
#include <hip/hip_runtime.h>

// Problem constants
#define NV 65536     // flattened vectors (64*32*32)
#define KN 1024      // codebook size
#define DD 256       // embedding dim
#define DECAY_F 0.99f
#define OMD_F (1.0f - 0.99f)
#define EPS_F 1e-5f

typedef __attribute__((ext_vector_type(8))) short short8;
typedef __attribute__((ext_vector_type(16))) float f32x16;

// ---------------------------------------------------------------------------
// async global->LDS 16B copy. LDS dest is wave-uniform base; HW writes
// base + lane*16.
// ---------------------------------------------------------------------------
__device__ __forceinline__ void gl_lds16(const void* g, void* l) {
  __builtin_amdgcn_global_load_lds(
      (const __attribute__((address_space(1))) unsigned int*)g,
      (__attribute__((address_space(3))) unsigned int*)l, 16, 0, 0);
}

// ---------------------------------------------------------------------------
// bf16 split helpers (RTNE) — identical arithmetic to the old split_x path,
// so in-kernel conversion yields bit-identical fragments.
// ---------------------------------------------------------------------------
__device__ __forceinline__ void bf16_split(float v, short& hi, short& lo) {
  unsigned u = __float_as_uint(v);
  unsigned hr = (u + 0x7FFFu + ((u >> 16) & 1u)) >> 16;
  float hf = __uint_as_float(hr << 16);
  float rem = v - hf;
  unsigned u2 = __float_as_uint(rem);
  unsigned lr = (u2 + 0x7FFFu + ((u2 >> 16) & 1u)) >> 16;
  hi = (short)hr;
  lo = (short)lr;
}

__device__ __forceinline__ void split8(float4 a, float4 b, short8& h,
                                       short8& l) {
  float v[8] = {a.x, a.y, a.z, a.w, b.x, b.y, b.z, b.w};
  #pragma unroll
  for (int j = 0; j < 8; j++) {
    short hh, ll;
    bf16_split(v[j], hh, ll);
    h[j] = hh; l[j] = ll;
  }
}

// ---------------------------------------------------------------------------
// Kernel 0: prep_e (blocks 0..31) + esq (32..287) + ws-zeroing (288..545).
// split_x is GONE — argmin converts x on the fly (R10).
// ---------------------------------------------------------------------------
__global__ __launch_bounds__(256) void prep_small(
    const float* __restrict__ emb, short* __restrict__ eT,
    float* __restrict__ eSq, float* __restrict__ zeroBase) {
  const int b = blockIdx.x;
  if (b < 32) {
    // ---- prep_e: e -> MFMA tiled layout.
    // 32 tiles (cc 0..3, dc 0..7), each 16384 shorts:
    //   [h(2)][db(4)][code(256)][8]  global code = cc*256+code, d=dc*32+db*8+j
    const int cc = b >> 3, dc = b & 7;
    const int c = threadIdx.x;  // code within chunk, 0..255
    const float* src = emb + (cc * 256 + c) * 256 + dc * 32;
    short* tile = eT + b * 16384;
    #pragma unroll
    for (int db = 0; db < 4; db++) {
      float v[8];
      *(float4*)(v + 0) = *(const float4*)(src + db * 8);
      *(float4*)(v + 4) = *(const float4*)(src + db * 8 + 4);
      short8 h, l;
      #pragma unroll
      for (int j = 0; j < 8; j++) {
        short hh, ll;
        bf16_split(v[j], hh, ll);
        h[j] = hh; l[j] = ll;
      }
      *(short8*)(tile + ((0 * 4 + db) * 256 + c) * 8) = h;
      *(short8*)(tile + ((1 * 4 + db) * 256 + c) * 8) = l;
    }
  } else if (b < 288) {
    // ---- esq: eSq[k] = ||embedding[k]||^2 (fp32). One wave per row. ----
    const int lane = threadIdx.x & 63;
    const int row = (b - 32) * 4 + (threadIdx.x >> 6);
    const float4 v = *(const float4*)(emb + row * DD + lane * 4);
    float s = v.x * v.x + v.y * v.y + v.z * v.z + v.w * v.w;
    #pragma unroll
    for (int off = 32; off > 0; off >>= 1) s += __shfl_down(s, off, 64);
    if (lane == 0) eSq[row] = s;
  } else {
    // ---- zero sseSlots(256) + cntI(1024) + dw(262144) = 263424 floats ----
    const int i = ((b - 288) * 256 + threadIdx.x) * 4;
    if (i < 263424)
      *(float4*)(zeroBase + i) = make_float4(0.0f, 0.0f, 0.0f, 0.0f);
  }
}

// ---------------------------------------------------------------------------
// Kernel 1: MFMA distance + exact best-2 + FUSED fp32 rescue/gather epilogue.
// R10 deltas vs R8 (126.5 us anchor):
//  (a) A-fragments converted from fp32 x IN-KERNEL (split_x eliminated).
//      Raw float4s loaded pre-barrier (same 4 VMEM ops -> vmcnt counts
//      unchanged); bf16_split runs post-barrier, VALU overlaps MFMA pipe.
//  (b) gather_rescue fused as a per-wave epilogue: each wave rescues its own
//      32 queries (shfl-broadcast candidates, wave-cooperative fp32 check),
//      writes outQ/outCodes/idxFinal + SSE/histogram atomics. cand is gone.
//  Counted-vmcnt double-buffer schedule is R8-verbatim.
// ---------------------------------------------------------------------------
__global__ __launch_bounds__(256, 2) void argmin_mfma(
    const float* __restrict__ x, const float* __restrict__ emb,
    const short* __restrict__ eT, const float* __restrict__ eSq,
    float* __restrict__ outQ, float* __restrict__ outCodes,
    int* __restrict__ idxFinal, float* __restrict__ sseSlots,
    int* __restrict__ cntI) {
  __shared__ __align__(16) char uS[67584];  // union: 2x32K stage / 66K fold
  __shared__ float eSqS[1024];

  float2* dbAll = (float2*)uS;

  const int tid = threadIdx.x;
  const int lane = tid & 63;
  const int wid = tid >> 6;
  const int l31 = lane & 31;
  const int lh = lane >> 5;
  const int qBase = blockIdx.x * 128 + wid * 32;

  // stage eSq once (1024 floats)
  *(float4*)(eSqS + tid * 4) = *(const float4*)(eSq + tid * 4);
  __syncthreads();  // eSqS visible to all waves BEFORE first es2 read

  float2* dbW = dbAll + wid * (64 * 33);

  float b1d = 3.4e38f, b2d = 3.4e38f;
  int b1k = 0, b2k = 1;

  const int qRow = (qBase + l31) * DD;   // fits 32-bit (16.7M max)

  const int wbase = wid * 1024;   // wave-uniform LDS sub-base (stage split)
  const int lane16 = lane * 16;   // per-lane global offset

  for (int cc = 0; cc < 4; cc++) {
    __syncthreads();  // prev-cc fold reads done / eSqS visible (cc=0)

    // prologue: stage tile (cc,0) into buf0 (8 VMEM ops outstanding)
    {
      const char* src = (const char*)(eT + (cc * 8 + 0) * 16384);
      #pragma unroll
      for (int i = 0; i < 8; i++)
        gl_lds16(src + i * 4096 + wbase + lane16, uS + i * 4096 + wbase);
    }

    f32x16 acc[8];
    #pragma unroll
    for (int ct = 0; ct < 8; ct++)
      #pragma unroll
      for (int i = 0; i < 16; i++) acc[ct][i] = 0.0f;

    float es2[8];
    #pragma unroll
    for (int ct = 0; ct < 8; ct++) es2[ct] = eSqS[cc * 256 + ct * 32 + l31];

    for (int dc = 0; dc < 8; dc++) {
      const int cur = dc & 1;
      const short* eS = (const short*)(uS + cur * 32768);

      // Raw A-data (4 float4 VMEM loads — same VMEM count as R8's short8s),
      // pinned BEFORE the stage-next block for deterministic vmcnt math.
      float4 ra0, rb0, ra1, rb1;
      {
        const float* xr = x + qRow + dc * 32 + lh * 8;
        ra0 = *(const float4*)(xr);
        rb0 = *(const float4*)(xr + 4);
        ra1 = *(const float4*)(xr + 16);
        rb1 = *(const float4*)(xr + 20);
      }
      __builtin_amdgcn_sched_barrier(0);

      if (dc < 7) {
        const char* src = (const char*)(eT + (cc * 8 + dc + 1) * 16384);
        char* dst = uS + (cur ^ 1) * 32768;
        #pragma unroll
        for (int i = 0; i < 8; i++)
          gl_lds16(src + i * 4096 + wbase + lane16, dst + i * 4096 + wbase);
        // outstanding: tile_dc(8 oldest) + A(4) + stage_next(8) = 20
        asm volatile("s_waitcnt vmcnt(12)" ::: "memory");
      } else {
        // outstanding: tile_7(8) + A(4) = 12
        asm volatile("s_waitcnt vmcnt(4)" ::: "memory");
      }
      __builtin_amdgcn_s_barrier();   // all waves: tile dc fully in LDS
      asm volatile("" ::: "memory");

      // convert raw fp32 -> bf16 hi/lo fragments (VALU; overlaps MFMA pipe)
      short8 ahi0, alo0, ahi1, alo1;
      split8(ra0, rb0, ahi0, alo0);
      split8(ra1, rb1, ahi1, alo1);

      // MFMA phase on buf[cur]
      #pragma unroll
      for (int ks = 0; ks < 2; ks++) {
        const short8 ahi = ks ? ahi1 : ahi0;
        const short8 alo = ks ? alo1 : alo0;
        const int db = ks * 2 + lh;
        #pragma unroll
        for (int ct = 0; ct < 8; ct++) {
          const int cL = ct * 32 + l31;
          const short8 bhi = *(const short8*)(eS + ((0 * 4 + db) * 256 + cL) * 8);
          const short8 blo = *(const short8*)(eS + ((1 * 4 + db) * 256 + cL) * 8);
          acc[ct] = __builtin_amdgcn_mfma_f32_32x32x16_bf16(ahi, bhi, acc[ct], 0, 0, 0);
          acc[ct] = __builtin_amdgcn_mfma_f32_32x32x16_bf16(ahi, blo, acc[ct], 0, 0, 0);
          acc[ct] = __builtin_amdgcn_mfma_f32_32x32x16_bf16(alo, bhi, acc[ct], 0, 0, 0);
        }
      }

      asm volatile("" ::: "memory");
      __builtin_amdgcn_s_barrier();   // all waves done reading buf[cur]
      asm volatile("" ::: "memory");
    }

    __syncthreads();  // all waves past MFMA reads; uS becomes fold buffer

    // per-(lane,reg): exact best2 over the 8 ct codes; transpose via LDS.
    #pragma unroll
    for (int r = 0; r < 16; r++) {
      const int row = (r & 3) + 8 * (r >> 2) + 4 * lh;  // query row 0..31
      float cb1 = 3.4e38f, cb2 = 3.4e38f;
      int ck1 = 0, ck2 = 0;
      #pragma unroll
      for (int ct = 0; ct < 8; ct++) {
        const float dd = es2[ct] - 2.0f * acc[ct][r];
        const int k = cc * 256 + ct * 32 + l31;
        if (dd < cb1) { cb2 = cb1; ck2 = ck1; cb1 = dd; ck1 = k; }
        else if (dd < cb2) { cb2 = dd; ck2 = k; }
      }
      dbW[(l31 * 2 + 0) * 33 + row] = make_float2(cb1, __int_as_float(ck1));
      dbW[(l31 * 2 + 1) * 33 + row] = make_float2(cb2, __int_as_float(ck2));
    }
    __syncthreads();  // transpose visible

    #pragma unroll
    for (int i = 0; i < 32; i++) {
      const float2 c = dbW[(lh * 32 + i) * 33 + l31];
      const float dd = c.x;
      const int k = __float_as_int(c.y);
      if (dd < b1d) { b2d = b1d; b2k = b1k; b1d = dd; b1k = k; }
      else if (dd < b2d) { b2d = dd; b2k = k; }
    }
  }

  // merge lane pairs (l, l+32): exact best2 of the union, k-tiebreak
  {
    const float p1d = __shfl_xor(b1d, 32, 64);
    const int p1k = __shfl_xor(b1k, 32, 64);
    const float p2d = __shfl_xor(b2d, 32, 64);
    const int p2k = __shfl_xor(b2k, 32, 64);
    if ((p1d < b1d) || (p1d == b1d && p1k < b1k)) {
      b2d = b1d; b2k = b1k; b1d = p1d; b1k = p1k;
    } else if ((p1d < b2d) || (p1d == b2d && p1k < b2k)) {
      b2d = p1d; b2k = p1k;
    }
    if ((p2d < b1d) || (p2d == b1d && p2k < b1k)) {
      b2d = b1d; b2k = b1k; b1d = p2d; b1k = p2k;
    } else if ((p2d < b2d) || (p2d == b2d && p2k < b2k)) {
      b2d = p2d; b2k = p2k;
    }
  }

  // ---- FUSED rescue/gather epilogue: wave processes its own 32 queries ----
  // (lanes q and q+32 both hold query q's merged best2; shfl broadcasts it)
  for (int q = 0; q < 32; q++) {
    const int k1 = __shfl(b1k, q, 64);
    const int k2 = __shfl(b2k, q, 64);
    const int n = qBase + q;

    const float4 xv = *(const float4*)(x + n * DD + lane * 4);
    const float4 e1 = *(const float4*)(emb + k1 * DD + lane * 4);
    const float4 e2 = *(const float4*)(emb + k2 * DD + lane * 4);

    float p1 = e1.x * (e1.x - 2.0f * xv.x) + e1.y * (e1.y - 2.0f * xv.y) +
               e1.z * (e1.z - 2.0f * xv.z) + e1.w * (e1.w - 2.0f * xv.w);
    float p2 = e2.x * (e2.x - 2.0f * xv.x) + e2.y * (e2.y - 2.0f * xv.y) +
               e2.z * (e2.z - 2.0f * xv.z) + e2.w * (e2.w - 2.0f * xv.w);
    #pragma unroll
    for (int m = 32; m > 0; m >>= 1) {
      p1 += __shfl_xor(p1, m, 64);
      p2 += __shfl_xor(p2, m, 64);
    }
    const bool pick2 = (p2 < p1) || (p2 == p1 && k2 < k1);
    const int ksel = pick2 ? k2 : k1;
    const float4 ev = pick2 ? e2 : e1;

    *(float4*)(outQ + n * DD + lane * 4) = ev;

    const float d0 = ev.x - xv.x, d1 = ev.y - xv.y, d2 = ev.z - xv.z,
                d3 = ev.w - xv.w;
    float s = d0 * d0 + d1 * d1 + d2 * d2 + d3 * d3;
    #pragma unroll
    for (int m = 32; m > 0; m >>= 1) s += __shfl_down(s, m, 64);
    if (lane == 0) {
      atomicAdd(&sseSlots[n & 255], s);
      atomicAdd(&cntI[ksel], 1);
      idxFinal[n] = ksel;
      outCodes[n] = (float)ksel;
    }
  }
}

// ---------------------------------------------------------------------------
// Kernel 2: FUSED scan + finalize1 + scatter. Single 1024-thread block.
// Scan cntI in LDS -> LDS cursors; new_cluster_size/n/norm/losses; then the
// same block scatters all 65536 indices via LDS atomics (512 KB traffic).
// Replaces scan_fin + scatter_kernel (one boundary + global cursor gone).
// ---------------------------------------------------------------------------
__global__ __launch_bounds__(1024) void scan_scatter_fin(
    const int* __restrict__ cntI, const float* __restrict__ ema_cs,
    const float* __restrict__ sseSlots, const int* __restrict__ idxFinal,
    int* __restrict__ perm, float* __restrict__ norm,
    float* __restrict__ outCS, float* __restrict__ outLoss) {
  __shared__ int si[1024];
  __shared__ int cur[1024];
  __shared__ float red[1024];
  const int t = threadIdx.x;
  const int v = cntI[t];
  si[t] = v;
  __syncthreads();
  #pragma unroll
  for (int off = 1; off < 1024; off <<= 1) {
    const int add = (t >= off) ? si[t - off] : 0;
    __syncthreads();
    si[t] += add;
    __syncthreads();
  }
  cur[t] = si[t] - v;  // exclusive prefix = segment start

  // finalize1 part
  const float ncs = DECAY_F * ema_cs[t] + OMD_F * (float)v;
  outCS[t] = ncs;
  red[t] = ncs;
  __syncthreads();
  #pragma unroll
  for (int s = 512; s > 0; s >>= 1) {
    if (t < s) red[t] += red[t + s];
    __syncthreads();
  }
  const float n = red[0];
  __syncthreads();
  norm[t] = (ncs + EPS_F) / (n + (float)KN * EPS_F) * n;

  red[t] = (t < 256) ? sseSlots[t] : 0.0f;
  __syncthreads();
  #pragma unroll
  for (int s = 512; s > 0; s >>= 1) {
    if (t < s) red[t] += red[t + s];
    __syncthreads();
  }
  if (t == 0) {
    const float mse = red[0] * (1.0f / 16777216.0f);
    outLoss[0] = 0.25f * mse;  // commitment
    outLoss[1] = mse;          // codebook
  }
  __syncthreads();  // cur[] final before scatter

  // scatter: counting sort into perm, LDS cursors
  for (int i = t; i < NV; i += 1024) {
    const int k = idxFinal[i];
    const int pos = atomicAdd(&cur[k], 1);
    perm[pos] = (k << 16) | i;
  }
}

// ---------------------------------------------------------------------------
// Kernel 3: BALANCED low-atomic segmented sum. (R8 verbatim)
// 512 blocks x 4 waves; each wave owns 32 CONSECUTIVE sorted rows.
// ---------------------------------------------------------------------------
__global__ __launch_bounds__(256) void dw_sum(const float* __restrict__ x,
                                              const int* __restrict__ perm,
                                              float* __restrict__ dw) {
  __shared__ int sp[128];
  const int tid = threadIdx.x;
  if (tid < 128) sp[tid] = perm[blockIdx.x * 128 + tid];
  __syncthreads();
  const int w = tid >> 6;
  const int l = tid & 63;
  const int* wp = sp + w * 32;

  float4 acc = make_float4(0.0f, 0.0f, 0.0f, 0.0f);
  int kcur = wp[0] >> 16;

  #pragma unroll
  for (int c = 0; c < 4; c++) {
    float4 v[8];
    int kk[8];
    #pragma unroll
    for (int j = 0; j < 8; j++) {
      const int p = wp[c * 8 + j];
      kk[j] = p >> 16;
      v[j] = *(const float4*)(x + (long)(p & 0xFFFF) * DD + l * 4);
    }
    #pragma unroll
    for (int j = 0; j < 8; j++) {
      if (kk[j] != kcur) {
        float* drow = dw + kcur * DD + l * 4;
        atomicAdd(drow + 0, acc.x);
        atomicAdd(drow + 1, acc.y);
        atomicAdd(drow + 2, acc.z);
        atomicAdd(drow + 3, acc.w);
        acc = make_float4(0.0f, 0.0f, 0.0f, 0.0f);
        kcur = kk[j];
      }
      acc.x += v[j].x; acc.y += v[j].y;
      acc.z += v[j].z; acc.w += v[j].w;
    }
  }
  {
    float* drow = dw + kcur * DD + l * 4;
    atomicAdd(drow + 0, acc.x);
    atomicAdd(drow + 1, acc.y);
    atomicAdd(drow + 2, acc.z);
    atomicAdd(drow + 3, acc.w);
  }
}

// ---------------------------------------------------------------------------
// Kernel 4: new_ema_w and new_embedding. (unchanged)
// ---------------------------------------------------------------------------
__global__ __launch_bounds__(256) void finalize2(
    const float* __restrict__ ema_w, const float* __restrict__ dw,
    const float* __restrict__ norm, float* __restrict__ outEmb,
    float* __restrict__ outW) {
  const int i = blockIdx.x * 256 + threadIdx.x;  // 0..262143
  const float nw = DECAY_F * ema_w[i] + OMD_F * dw[i];
  outW[i] = nw;
  outEmb[i] = nw / norm[i >> 8];
}

// ---------------------------------------------------------------------------
extern "C" void kernel_launch(void* const* d_in, const int* in_sizes, int n_in,
                              void* d_out, int out_size, void* d_ws, size_t ws_size,
                              hipStream_t stream) {
  const float* x = (const float*)d_in[0];        // [65536, 256]
  const float* emb = (const float*)d_in[1];      // [1024, 256]
  const float* ema_cs = (const float*)d_in[2];   // [1024]
  const float* ema_w = (const float*)d_in[3];    // [1024, 256]
  float* out = (float*)d_out;
  float* ws = (float*)d_ws;

  // --- workspace (float offsets) ---
  float* eSq = ws + 0;                   // 1024
  float* sseSlots = ws + 1024;           // 256   (zeroed by prep_small)
  int* cntI = (int*)(ws + 1280);         // 1024 ints (zeroed by prep_small)
  float* dw = ws + 2304;                 // 262144 (zeroed by prep_small)
  float* norm = ws + 264448;             // 1024
  int* idxFinal = (int*)(ws + 265472);   // 65536 ints
  int* perm = (int*)(ws + 331008);       // 65536 ints (packed (k<<16)|n)

  // --- final output layout (return-order flat, fp32) ---
  float* outQ = out;                    // 16777216  quantized_st
  float* outCodes = out + 16777216;     // 65536     codes (as float)
  float* outLoss = out + 16842752;      // 2         commitment, codebook
  float* outEmb = out + 16842754;       // 262144    new_embedding
  float* outCS = out + 17104898;        // 1024      new_cluster_size
  float* outW = out + 17105922;         // 262144    new_ema_w

  // eT scratch lives in the LATE-WRITTEN outEmb zone (written only by
  // finalize2, which runs after argmin_mfma finished reading eT).
  // out+16842756 is 16B-aligned; spans to 17104900 (2 floats into outCS,
  // which scan_scatter_fin writes after argmin completes — stream-safe).
  short* eT = (short*)(out + 16842756);  // 524288 shorts (1 MB)

  prep_small<<<546, 256, 0, stream>>>(emb, eT, eSq, ws + 1024);
  argmin_mfma<<<NV / 128, 256, 0, stream>>>(x, emb, eT, eSq, outQ, outCodes,
                                            idxFinal, sseSlots, cntI);
  scan_scatter_fin<<<1, 1024, 0, stream>>>(cntI, ema_cs, sseSlots, idxFinal,
                                           perm, norm, outCS, outLoss);
  dw_sum<<<NV / 128, 256, 0, stream>>>(x, perm, dw);
  finalize2<<<KN * DD / 256, 256, 0, stream>>>(ema_w, dw, norm, outEmb, outW);
}